// Round 1
// baseline (738.960 us; speedup 1.0000x reference)
//
#include <hip/hip_runtime.h>
#include <hip/hip_bf16.h>

#define NTOK 1024
#define DM 768
#define NEXP 16
#define FFN 3072
#define NSLOT 4096
#define SLOTPAD 4112

typedef __bf16 bf16x8 __attribute__((ext_vector_type(8)));
typedef float f32x4 __attribute__((ext_vector_type(4)));

// round-to-nearest-even fp32 -> bf16 (no NaN path needed: data is finite)
static __device__ __forceinline__ unsigned short f2bf(float f){
  unsigned u = __builtin_bit_cast(unsigned, f);
  u += 0x7fffu + ((u >> 16) & 1u);
  return (unsigned short)(u >> 16);
}

// ---------------- init: zero expert counts ----------------
__global__ void k_init(int* counts){
  if (threadIdx.x < NEXP) counts[threadIdx.x] = 0;
}

// ---------------- router: logits, softmax, top-4, renorm ----------------
__global__ __launch_bounds__(64) void k_router(const float* __restrict__ x,
    const float* __restrict__ rw, int* counts, int* topk_e, float* topk_w){
  const int t = blockIdx.x;
  const int lane = threadIdx.x;
  float acc[NEXP];
  #pragma unroll
  for (int e = 0; e < NEXP; e++) acc[e] = 0.f;
  const float* xr = x + (size_t)t * DM;
  for (int d = lane; d < DM; d += 64){
    float xv = xr[d];
    #pragma unroll
    for (int e = 0; e < NEXP; e++) acc[e] = fmaf(xv, rw[e * DM + d], acc[e]);
  }
  #pragma unroll
  for (int e = 0; e < NEXP; e++){
    float v = acc[e];
    #pragma unroll
    for (int off = 32; off; off >>= 1) v += __shfl_xor(v, off, 64);
    acc[e] = v;
  }
  if (lane == 0){
    float mx = -1e30f;
    #pragma unroll
    for (int e = 0; e < NEXP; e++) mx = fmaxf(mx, acc[e]);
    float p[NEXP];
    #pragma unroll
    for (int e = 0; e < NEXP; e++) p[e] = __expf(acc[e] - mx);
    // top-4 by p (monotone with logits; ties -> lowest index, matches top_k)
    int ids[4]; float wv[4]; float wsum = 0.f;
    for (int k = 0; k < 4; k++){
      float best = -1.f; int bi = 0;
      #pragma unroll
      for (int e = 0; e < NEXP; e++) if (p[e] > best){ best = p[e]; bi = e; }
      ids[k] = bi; wv[k] = best; wsum += best; p[bi] = -2.f;
    }
    float inv = 1.f / wsum;
    for (int k = 0; k < 4; k++){
      topk_e[t * 4 + k] = ids[k];
      topk_w[t * 4 + k] = wv[k] * inv;
      atomicAdd(&counts[ids[k]], 1);
    }
  }
}

// ---------------- offsets: exclusive prefix over 16 experts ----------------
__global__ void k_offsets(const int* counts, int* offs, int* cursor){
  if (threadIdx.x == 0){
    int s = 0;
    for (int e = 0; e < NEXP; e++){ offs[e] = s; cursor[e] = s; s += counts[e]; }
    offs[NEXP] = s;  // == 4096
  }
}

// ---------------- assign slots ----------------
__global__ __launch_bounds__(256) void k_assign(const int* __restrict__ topk_e,
    int* cursor, int* tokmap, int* tokslot){
  int t = blockIdx.x * 256 + threadIdx.x;
  if (t < NTOK){
    for (int k = 0; k < 4; k++){
      int e = topk_e[t * 4 + k];
      int pos = atomicAdd(&cursor[e], 1);
      tokmap[pos] = t;
      tokslot[t * 4 + k] = pos;
    }
  }
}

// ---------------- gather x rows per slot, fp32 -> bf16 ----------------
__global__ __launch_bounds__(192) void k_gather(const float* __restrict__ x,
    const int* __restrict__ tokmap, unsigned short* __restrict__ xg){
  const int s = blockIdx.x;
  const int j = threadIdx.x;           // 0..191, 4 floats each
  const int t = tokmap[s];
  float4 v = reinterpret_cast<const float4*>(x + (size_t)t * DM)[j];
  ushort4 o; o.x = f2bf(v.x); o.y = f2bf(v.y); o.z = f2bf(v.z); o.w = f2bf(v.w);
  reinterpret_cast<ushort4*>(xg + (size_t)s * DM)[j] = o;
}

// ---------------- phase 1: gate/up GEMM + SiLU-GLU ----------------
// block = (itile of 16 FFN rows, expert). B (w1,v1 slices) LDS-resident, read once.
// A fragments loaded directly from global xg in MFMA A-layout.
#define P1S 776   // 768 + 8 pad (bf16 elems); row stride 1552 B, 16B-aligned, 2-way banks (free)
__global__ __launch_bounds__(256, 3) void k_ffn1(const float* __restrict__ w1,
    const float* __restrict__ v1, const unsigned short* __restrict__ xg,
    unsigned short* __restrict__ act, const int* __restrict__ offs){
  __shared__ unsigned short bw[2][16][P1S];
  const int e  = blockIdx.y;
  const int i0 = blockIdx.x * 16;
  const int tid = threadIdx.x;
  {
    const float* s0 = w1 + ((size_t)e * FFN + i0) * DM;
    const float* s1 = v1 + ((size_t)e * FFN + i0) * DM;
    #pragma unroll
    for (int tt = 0; tt < 12; tt++){
      int idx = tid + tt * 256;          // 0..3071 float4 index
      int row = idx / 192;
      int c4  = idx - row * 192;
      float4 a = *reinterpret_cast<const float4*>(s0 + (size_t)row * DM + c4 * 4);
      float4 b = *reinterpret_cast<const float4*>(s1 + (size_t)row * DM + c4 * 4);
      ushort4 oa; oa.x = f2bf(a.x); oa.y = f2bf(a.y); oa.z = f2bf(a.z); oa.w = f2bf(a.w);
      ushort4 ob; ob.x = f2bf(b.x); ob.y = f2bf(b.y); ob.z = f2bf(b.z); ob.w = f2bf(b.w);
      *reinterpret_cast<ushort4*>(&bw[0][row][c4 * 4]) = oa;
      *reinterpret_cast<ushort4*>(&bw[1][row][c4 * 4]) = ob;
    }
  }
  __syncthreads();
  const int base = offs[e];
  const int cnt  = offs[e + 1] - base;
  const int nmt  = (cnt + 15) >> 4;
  const int wid = tid >> 6, lane = tid & 63;
  const int n = lane & 15, quad = lane >> 4;
  const unsigned short* b0p = &bw[0][n][quad * 8];
  const unsigned short* b1p = &bw[1][n][quad * 8];
  for (int mt = wid; mt < nmt; mt += 4){
    const unsigned short* ap = xg + (size_t)(base + mt * 16 + n) * DM + quad * 8;
    f32x4 accg = {0.f, 0.f, 0.f, 0.f}, accu = {0.f, 0.f, 0.f, 0.f};
    #pragma unroll 4
    for (int k = 0; k < 24; k++){
      bf16x8 a = *reinterpret_cast<const bf16x8*>(ap + k * 32);
      bf16x8 g = *reinterpret_cast<const bf16x8*>(b0p + k * 32);
      bf16x8 u = *reinterpret_cast<const bf16x8*>(b1p + k * 32);
      accg = __builtin_amdgcn_mfma_f32_16x16x32_bf16(a, g, accg, 0, 0, 0);
      accu = __builtin_amdgcn_mfma_f32_16x16x32_bf16(a, u, accu, 0, 0, 0);
    }
    // C/D layout: col(lane&15)=FFN col, row=quad*4+r = token-slot offset
    #pragma unroll
    for (int r = 0; r < 4; r++){
      int rowi = mt * 16 + quad * 4 + r;
      if (rowi < cnt){
        float gv = accg[r], uv = accu[r];
        float sv = gv / (1.f + __expf(-gv));   // SiLU
        act[(size_t)(base + rowi) * FFN + i0 + n] = f2bf(sv * uv);
      }
    }
  }
}

// ---------------- phase 2: down GEMM, per-slot output ----------------
// block = (dtile of 32 D cols, expert). Accumulates ALL expert tokens (320 cap)
// while streaming w2 once through double-buffered LDS K-chunks of 128.
#define P2S 136   // 128 + 8 pad (bf16); row stride 272 B, 16B-aligned, 2-way banks (free)
__global__ __launch_bounds__(256, 2) void k_ffn2(const float* __restrict__ w2,
    const unsigned short* __restrict__ act, float* __restrict__ outs,
    const int* __restrict__ offs){
  __shared__ unsigned short bs[2][32][P2S];
  const int e  = blockIdx.y;
  const int d0 = blockIdx.x * 32;
  const int tid = threadIdx.x;
  const int wid = tid >> 6, lane = tid & 63;
  const int n = lane & 15, quad = lane >> 4;
  const int base = offs[e];
  const int cnt  = offs[e + 1] - base;
  const int nsb  = (cnt + 319) / 320;
  const float* bsrc = w2 + ((size_t)e * DM + d0) * FFN;
  for (int sb = 0; sb < nsb; sb++){
    f32x4 acc[5][2];
    #pragma unroll
    for (int j = 0; j < 5; j++){
      acc[j][0] = (f32x4){0.f, 0.f, 0.f, 0.f};
      acc[j][1] = (f32x4){0.f, 0.f, 0.f, 0.f};
    }
    const unsigned short* actp[5];
    bool rok[5];
    #pragma unroll
    for (int j = 0; j < 5; j++){
      int rowbase = sb * 320 + (wid + j * 4) * 16;
      rok[j] = rowbase < cnt;
      actp[j] = act + (size_t)(base + rowbase + n) * FFN;
    }
    // stage K-chunk 0
    #pragma unroll
    for (int tt = 0; tt < 4; tt++){
      int idx = tid + tt * 256;
      int row = idx >> 5, kf = idx & 31;
      float4 v = *reinterpret_cast<const float4*>(bsrc + (size_t)row * FFN + kf * 4);
      ushort4 o; o.x = f2bf(v.x); o.y = f2bf(v.y); o.z = f2bf(v.z); o.w = f2bf(v.w);
      *reinterpret_cast<ushort4*>(&bs[0][row][kf * 4]) = o;
    }
    for (int kc = 0; kc < 24; kc++){
      const int cur = kc & 1;
      float4 pf[4];
      if (kc < 23){
        #pragma unroll
        for (int tt = 0; tt < 4; tt++){
          int idx = tid + tt * 256;
          int row = idx >> 5, kf = idx & 31;
          pf[tt] = *reinterpret_cast<const float4*>(bsrc + (size_t)row * FFN + (kc + 1) * 128 + kf * 4);
        }
      }
      __syncthreads();   // bs[cur] ready; prev readers of bs[cur^1] done
      #pragma unroll
      for (int kl = 0; kl < 4; kl++){
        bf16x8 b0 = *reinterpret_cast<const bf16x8*>(&bs[cur][n][kl * 32 + quad * 8]);
        bf16x8 b1 = *reinterpret_cast<const bf16x8*>(&bs[cur][16 + n][kl * 32 + quad * 8]);
        #pragma unroll
        for (int j = 0; j < 5; j++){
          if (rok[j]){
            bf16x8 a = *reinterpret_cast<const bf16x8*>(actp[j] + kc * 128 + kl * 32 + quad * 8);
            acc[j][0] = __builtin_amdgcn_mfma_f32_16x16x32_bf16(a, b0, acc[j][0], 0, 0, 0);
            acc[j][1] = __builtin_amdgcn_mfma_f32_16x16x32_bf16(a, b1, acc[j][1], 0, 0, 0);
          }
        }
      }
      if (kc < 23){
        #pragma unroll
        for (int tt = 0; tt < 4; tt++){
          int idx = tid + tt * 256;
          int row = idx >> 5, kf = idx & 31;
          ushort4 o; o.x = f2bf(pf[tt].x); o.y = f2bf(pf[tt].y); o.z = f2bf(pf[tt].z); o.w = f2bf(pf[tt].w);
          *reinterpret_cast<ushort4*>(&bs[cur ^ 1][row][kf * 4]) = o;
        }
      }
    }
    #pragma unroll
    for (int j = 0; j < 5; j++){
      if (!rok[j]) continue;
      int rowbase = sb * 320 + (wid + j * 4) * 16;
      #pragma unroll
      for (int ct = 0; ct < 2; ct++){
        #pragma unroll
        for (int r = 0; r < 4; r++){
          int rowi = rowbase + quad * 4 + r;
          if (rowi < cnt)
            outs[(size_t)(base + rowi) * DM + d0 + ct * 16 + n] = acc[j][ct][r];
        }
      }
    }
  }
}

// ---------------- combine: out[t] = sum_k w_k * outs[slot_k] ----------------
__global__ __launch_bounds__(192) void k_combine(const float* __restrict__ outs,
    const int* __restrict__ tokslot, const float* __restrict__ topk_w,
    float* __restrict__ out){
  const int t = blockIdx.x;
  const int j = threadIdx.x;  // 0..191
  float4 o = {0.f, 0.f, 0.f, 0.f};
  #pragma unroll
  for (int k = 0; k < 4; k++){
    int s = tokslot[t * 4 + k];
    float w = topk_w[t * 4 + k];
    float4 v = reinterpret_cast<const float4*>(outs + (size_t)s * DM)[j];
    o.x += w * v.x; o.y += w * v.y; o.z += w * v.z; o.w += w * v.w;
  }
  reinterpret_cast<float4*>(out + (size_t)t * DM)[j] = o;
}

// ---------------- workspace layout (bytes) ----------------
#define WS_COUNTS  0
#define WS_OFFS    64
#define WS_CURSOR  192
#define WS_TOPKE   256
#define WS_TOPKW   (WS_TOPKE + NSLOT * 4)
#define WS_TOKSLOT (WS_TOPKW + NSLOT * 4)
#define WS_TOKMAP  (WS_TOKSLOT + NSLOT * 4)
#define WS_XG      131072
#define WS_ACT     (WS_XG + (size_t)SLOTPAD * DM * 2)      // 6,447,104
#define WS_OUTS    (WS_ACT + (size_t)SLOTPAD * FFN * 2)    // 31,711,232
// total: WS_OUTS + 4096*768*4 = 44,294,144 bytes

extern "C" void kernel_launch(void* const* d_in, const int* in_sizes, int n_in,
                              void* d_out, int out_size, void* d_ws, size_t ws_size,
                              hipStream_t stream){
  const float* x  = (const float*)d_in[0];   // [1024, 768]
  const float* rw = (const float*)d_in[1];   // [16, 768]
  const float* w1 = (const float*)d_in[2];   // [16, 3072, 768]
  const float* v1 = (const float*)d_in[3];   // [16, 3072, 768]
  const float* w2 = (const float*)d_in[4];   // [16, 768, 3072]
  float* out = (float*)d_out;
  char* ws = (char*)d_ws;

  int*   counts  = (int*)(ws + WS_COUNTS);
  int*   offs    = (int*)(ws + WS_OFFS);
  int*   cursor  = (int*)(ws + WS_CURSOR);
  int*   topk_e  = (int*)(ws + WS_TOPKE);
  float* topk_w  = (float*)(ws + WS_TOPKW);
  int*   tokslot = (int*)(ws + WS_TOKSLOT);
  int*   tokmap  = (int*)(ws + WS_TOKMAP);
  unsigned short* xg  = (unsigned short*)(ws + WS_XG);
  unsigned short* act = (unsigned short*)(ws + WS_ACT);
  float* outs = (float*)(ws + WS_OUTS);

  k_init<<<dim3(1), dim3(64), 0, stream>>>(counts);
  k_router<<<dim3(NTOK), dim3(64), 0, stream>>>(x, rw, counts, topk_e, topk_w);
  k_offsets<<<dim3(1), dim3(64), 0, stream>>>(counts, offs, cursor);
  k_assign<<<dim3(4), dim3(256), 0, stream>>>(topk_e, cursor, tokmap, tokslot);
  k_gather<<<dim3(NSLOT), dim3(192), 0, stream>>>(x, tokmap, xg);
  k_ffn1<<<dim3(FFN / 16, NEXP), dim3(256), 0, stream>>>(w1, v1, xg, act, offs);
  k_ffn2<<<dim3(DM / 32, NEXP), dim3(256), 0, stream>>>(w2, act, outs, offs);
  k_combine<<<dim3(NTOK), dim3(192), 0, stream>>>(outs, tokslot, topk_w, out);
}

// Round 2
// 665.056 us; speedup vs baseline: 1.1111x; 1.1111x over previous
//
#include <hip/hip_runtime.h>
#include <hip/hip_bf16.h>

#define NTOK 1024
#define DM 768
#define NEXP 16
#define FFN 3072
#define NSLOT 4096
#define SLOTPAD 4112

typedef __bf16 bf16x8 __attribute__((ext_vector_type(8)));
typedef float f32x4 __attribute__((ext_vector_type(4)));

// round-to-nearest-even fp32 -> bf16 (no NaN path needed: data is finite)
static __device__ __forceinline__ unsigned short f2bf(float f){
  unsigned u = __builtin_bit_cast(unsigned, f);
  u += 0x7fffu + ((u >> 16) & 1u);
  return (unsigned short)(u >> 16);
}

// ---------------- router: logits, softmax, top-4, renorm ----------------
__global__ __launch_bounds__(64) void k_router(const float* __restrict__ x,
    const float* __restrict__ rw, int* topk_e, float* topk_w){
  const int t = blockIdx.x;
  const int lane = threadIdx.x;
  float4 xv[3];
  const float4* xr = reinterpret_cast<const float4*>(x + (size_t)t * DM);
  #pragma unroll
  for (int i = 0; i < 3; i++) xv[i] = xr[lane + i * 64];
  float acc[NEXP];
  #pragma unroll
  for (int e = 0; e < NEXP; e++){
    const float4* rp = reinterpret_cast<const float4*>(rw + e * DM);
    float s = 0.f;
    #pragma unroll
    for (int i = 0; i < 3; i++){
      float4 w = rp[lane + i * 64];
      s = fmaf(xv[i].x, w.x, s); s = fmaf(xv[i].y, w.y, s);
      s = fmaf(xv[i].z, w.z, s); s = fmaf(xv[i].w, w.w, s);
    }
    acc[e] = s;
  }
  #pragma unroll
  for (int e = 0; e < NEXP; e++){
    float v = acc[e];
    #pragma unroll
    for (int off = 32; off; off >>= 1) v += __shfl_xor(v, off, 64);
    acc[e] = v;
  }
  if (lane == 0){
    float mx = -1e30f;
    #pragma unroll
    for (int e = 0; e < NEXP; e++) mx = fmaxf(mx, acc[e]);
    float p[NEXP];
    #pragma unroll
    for (int e = 0; e < NEXP; e++) p[e] = __expf(acc[e] - mx);
    // top-4 by p (monotone with logits; ties -> lowest index, matches top_k)
    int ids[4]; float wv[4]; float wsum = 0.f;
    for (int k = 0; k < 4; k++){
      float best = -1.f; int bi = 0;
      #pragma unroll
      for (int e = 0; e < NEXP; e++) if (p[e] > best){ best = p[e]; bi = e; }
      ids[k] = bi; wv[k] = best; wsum += best; p[bi] = -2.f;
    }
    float inv = 1.f / wsum;
    for (int k = 0; k < 4; k++){
      topk_e[t * 4 + k] = ids[k];
      topk_w[t * 4 + k] = wv[k] * inv;
    }
  }
}

// ---------------- prep: histogram counts + exclusive prefix ----------------
__global__ __launch_bounds__(256) void k_prep(const int* __restrict__ topk_e,
    int* offs, int* cursor){
  __shared__ int cs[NEXP];
  const int tid = threadIdx.x;
  if (tid < NEXP) cs[tid] = 0;
  __syncthreads();
  for (int i = tid; i < NSLOT; i += 256) atomicAdd(&cs[topk_e[i]], 1);
  __syncthreads();
  if (tid == 0){
    int s = 0;
    for (int e = 0; e < NEXP; e++){ offs[e] = s; cursor[e] = s; s += cs[e]; }
    offs[NEXP] = s;  // == 4096
  }
}

// ---------------- assign slots + gather x rows (fp32 -> bf16) ----------------
__global__ __launch_bounds__(192) void k_assign_gather(const float* __restrict__ x,
    const int* __restrict__ topk_e, int* cursor, int* tokslot,
    unsigned short* __restrict__ xg){
  __shared__ int slot_s[4];
  const int t = blockIdx.x;
  const int tid = threadIdx.x;
  if (tid < 4){
    int e = topk_e[t * 4 + tid];
    int pos = atomicAdd(&cursor[e], 1);
    slot_s[tid] = pos;
    tokslot[t * 4 + tid] = pos;
  }
  __syncthreads();
  float4 v = reinterpret_cast<const float4*>(x + (size_t)t * DM)[tid];
  ushort4 o; o.x = f2bf(v.x); o.y = f2bf(v.y); o.z = f2bf(v.z); o.w = f2bf(v.w);
  #pragma unroll
  for (int k = 0; k < 4; k++)
    reinterpret_cast<ushort4*>(xg + (size_t)slot_s[k] * DM)[tid] = o;
}

// ---------------- phase 1: gate/up GEMM + SiLU-GLU ----------------
// block = (32 FFN cols, expert). Accumulates ALL expert tokens (320 cap)
// while streaming w1+v1 once through double-buffered LDS K-chunks of 128.
// A fragments read directly from global xg (L2-resident) in MFMA A-layout.
#define P1K 136   // 128 + 8 pad bf16; row stride 272 B (16B-aligned, 2-way banks = free)
__global__ __launch_bounds__(256, 2) void k_ffn1(const float* __restrict__ w1,
    const float* __restrict__ v1, const unsigned short* __restrict__ xg,
    unsigned short* __restrict__ act, const int* __restrict__ offs){
  __shared__ unsigned short bs[2][2][32][P1K];   // [dbuf][mat g/u][ffn col][k]
  const int e  = blockIdx.y;
  const int i0 = blockIdx.x * 32;
  const int tid = threadIdx.x;
  const int wid = tid >> 6, lane = tid & 63;
  const int n = lane & 15, quad = lane >> 4;
  const int base = offs[e];
  const int cnt  = offs[e + 1] - base;
  const int nsb  = (cnt + 319) / 320;
  const float* srcs[2] = { w1 + ((size_t)e * FFN + i0) * DM,
                           v1 + ((size_t)e * FFN + i0) * DM };
  // staging map: per mat, 32 rows x 32 float4; idx = tid + tt*256
  int srow[4], skf[4];
  #pragma unroll
  for (int tt = 0; tt < 4; tt++){ int idx = tid + tt * 256; srow[tt] = idx >> 5; skf[tt] = idx & 31; }

  for (int sb = 0; sb < nsb; sb++){
    f32x4 accg[5][2], accu[5][2];
    #pragma unroll
    for (int j = 0; j < 5; j++){
      accg[j][0] = (f32x4){0,0,0,0}; accg[j][1] = (f32x4){0,0,0,0};
      accu[j][0] = (f32x4){0,0,0,0}; accu[j][1] = (f32x4){0,0,0,0};
    }
    const unsigned short* ap[5]; bool rok[5];
    #pragma unroll
    for (int j = 0; j < 5; j++){
      int rb = sb * 320 + (wid + j * 4) * 16;
      rok[j] = rb < cnt;
      ap[j] = xg + (size_t)(base + rb + n) * DM;
    }
    // stage K-chunk 0 into bs[0]
    #pragma unroll
    for (int m = 0; m < 2; m++){
      #pragma unroll
      for (int tt = 0; tt < 4; tt++){
        float4 v = reinterpret_cast<const float4*>(srcs[m] + (size_t)srow[tt] * DM)[skf[tt]];
        ushort4 o; o.x = f2bf(v.x); o.y = f2bf(v.y); o.z = f2bf(v.z); o.w = f2bf(v.w);
        *reinterpret_cast<ushort4*>(&bs[0][m][srow[tt]][skf[tt] * 4]) = o;
      }
    }
    for (int kc = 0; kc < 6; kc++){
      const int cur = kc & 1;
      float4 pf[8];
      if (kc < 5){
        #pragma unroll
        for (int m = 0; m < 2; m++)
          #pragma unroll
          for (int tt = 0; tt < 4; tt++)
            pf[m * 4 + tt] = reinterpret_cast<const float4*>(
                srcs[m] + (size_t)srow[tt] * DM)[(kc + 1) * 32 + skf[tt]];
      }
      __syncthreads();   // bs[cur] writes visible; prior readers of bs[cur^1] done
      #pragma unroll
      for (int kl = 0; kl < 4; kl++){
        const int ko = kl * 32 + quad * 8;
        bf16x8 bg0 = *reinterpret_cast<const bf16x8*>(&bs[cur][0][n][ko]);
        bf16x8 bg1 = *reinterpret_cast<const bf16x8*>(&bs[cur][0][16 + n][ko]);
        bf16x8 bu0 = *reinterpret_cast<const bf16x8*>(&bs[cur][1][n][ko]);
        bf16x8 bu1 = *reinterpret_cast<const bf16x8*>(&bs[cur][1][16 + n][ko]);
        #pragma unroll
        for (int j = 0; j < 5; j++){
          if (rok[j]){
            bf16x8 a = *reinterpret_cast<const bf16x8*>(ap[j] + kc * 128 + ko);
            accg[j][0] = __builtin_amdgcn_mfma_f32_16x16x32_bf16(a, bg0, accg[j][0], 0, 0, 0);
            accg[j][1] = __builtin_amdgcn_mfma_f32_16x16x32_bf16(a, bg1, accg[j][1], 0, 0, 0);
            accu[j][0] = __builtin_amdgcn_mfma_f32_16x16x32_bf16(a, bu0, accu[j][0], 0, 0, 0);
            accu[j][1] = __builtin_amdgcn_mfma_f32_16x16x32_bf16(a, bu1, accu[j][1], 0, 0, 0);
          }
        }
      }
      if (kc < 5){
        #pragma unroll
        for (int m = 0; m < 2; m++){
          #pragma unroll
          for (int tt = 0; tt < 4; tt++){
            float4 v = pf[m * 4 + tt];
            ushort4 o; o.x = f2bf(v.x); o.y = f2bf(v.y); o.z = f2bf(v.z); o.w = f2bf(v.w);
            *reinterpret_cast<ushort4*>(&bs[cur ^ 1][m][srow[tt]][skf[tt] * 4]) = o;
          }
        }
      }
    }
    // epilogue: SiLU(gate) * up -> act bf16
    #pragma unroll
    for (int j = 0; j < 5; j++){
      if (!rok[j]) continue;
      int rb = sb * 320 + (wid + j * 4) * 16;
      #pragma unroll
      for (int ct = 0; ct < 2; ct++){
        #pragma unroll
        for (int r = 0; r < 4; r++){
          int rowi = rb + quad * 4 + r;
          if (rowi < cnt){
            float gv = accg[j][ct][r], uv = accu[j][ct][r];
            float sv = gv / (1.f + __expf(-gv));
            act[(size_t)(base + rowi) * FFN + i0 + ct * 16 + n] = f2bf(sv * uv);
          }
        }
      }
    }
  }
}

// ---------------- phase 2: down GEMM, per-slot output ----------------
#define P2S 136   // 128 + 8 pad (bf16)
__global__ __launch_bounds__(256, 2) void k_ffn2(const float* __restrict__ w2,
    const unsigned short* __restrict__ act, float* __restrict__ outs,
    const int* __restrict__ offs){
  __shared__ unsigned short bs[2][32][P2S];
  const int e  = blockIdx.y;
  const int d0 = blockIdx.x * 32;
  const int tid = threadIdx.x;
  const int wid = tid >> 6, lane = tid & 63;
  const int n = lane & 15, quad = lane >> 4;
  const int base = offs[e];
  const int cnt  = offs[e + 1] - base;
  const int nsb  = (cnt + 319) / 320;
  const float* bsrc = w2 + ((size_t)e * DM + d0) * FFN;
  for (int sb = 0; sb < nsb; sb++){
    f32x4 acc[5][2];
    #pragma unroll
    for (int j = 0; j < 5; j++){
      acc[j][0] = (f32x4){0.f, 0.f, 0.f, 0.f};
      acc[j][1] = (f32x4){0.f, 0.f, 0.f, 0.f};
    }
    const unsigned short* actp[5];
    bool rok[5];
    #pragma unroll
    for (int j = 0; j < 5; j++){
      int rowbase = sb * 320 + (wid + j * 4) * 16;
      rok[j] = rowbase < cnt;
      actp[j] = act + (size_t)(base + rowbase + n) * FFN;
    }
    // stage K-chunk 0
    #pragma unroll
    for (int tt = 0; tt < 4; tt++){
      int idx = tid + tt * 256;
      int row = idx >> 5, kf = idx & 31;
      float4 v = *reinterpret_cast<const float4*>(bsrc + (size_t)row * FFN + kf * 4);
      ushort4 o; o.x = f2bf(v.x); o.y = f2bf(v.y); o.z = f2bf(v.z); o.w = f2bf(v.w);
      *reinterpret_cast<ushort4*>(&bs[0][row][kf * 4]) = o;
    }
    for (int kc = 0; kc < 24; kc++){
      const int cur = kc & 1;
      float4 pf[4];
      if (kc < 23){
        #pragma unroll
        for (int tt = 0; tt < 4; tt++){
          int idx = tid + tt * 256;
          int row = idx >> 5, kf = idx & 31;
          pf[tt] = *reinterpret_cast<const float4*>(bsrc + (size_t)row * FFN + (kc + 1) * 128 + kf * 4);
        }
      }
      __syncthreads();   // bs[cur] ready; prev readers of bs[cur^1] done
      #pragma unroll
      for (int kl = 0; kl < 4; kl++){
        bf16x8 b0 = *reinterpret_cast<const bf16x8*>(&bs[cur][n][kl * 32 + quad * 8]);
        bf16x8 b1 = *reinterpret_cast<const bf16x8*>(&bs[cur][16 + n][kl * 32 + quad * 8]);
        #pragma unroll
        for (int j = 0; j < 5; j++){
          if (rok[j]){
            bf16x8 a = *reinterpret_cast<const bf16x8*>(actp[j] + kc * 128 + kl * 32 + quad * 8);
            acc[j][0] = __builtin_amdgcn_mfma_f32_16x16x32_bf16(a, b0, acc[j][0], 0, 0, 0);
            acc[j][1] = __builtin_amdgcn_mfma_f32_16x16x32_bf16(a, b1, acc[j][1], 0, 0, 0);
          }
        }
      }
      if (kc < 23){
        #pragma unroll
        for (int tt = 0; tt < 4; tt++){
          int idx = tid + tt * 256;
          int row = idx >> 5, kf = idx & 31;
          ushort4 o; o.x = f2bf(pf[tt].x); o.y = f2bf(pf[tt].y); o.z = f2bf(pf[tt].z); o.w = f2bf(pf[tt].w);
          *reinterpret_cast<ushort4*>(&bs[cur ^ 1][row][kf * 4]) = o;
        }
      }
    }
    #pragma unroll
    for (int j = 0; j < 5; j++){
      if (!rok[j]) continue;
      int rowbase = sb * 320 + (wid + j * 4) * 16;
      #pragma unroll
      for (int ct = 0; ct < 2; ct++){
        #pragma unroll
        for (int r = 0; r < 4; r++){
          int rowi = rowbase + quad * 4 + r;
          if (rowi < cnt)
            outs[(size_t)(base + rowi) * DM + d0 + ct * 16 + n] = acc[j][ct][r];
        }
      }
    }
  }
}

// ---------------- combine: out[t] = sum_k w_k * outs[slot_k] ----------------
__global__ __launch_bounds__(192) void k_combine(const float* __restrict__ outs,
    const int* __restrict__ tokslot, const float* __restrict__ topk_w,
    float* __restrict__ out){
  const int t = blockIdx.x;
  const int j = threadIdx.x;  // 0..191
  float4 o = {0.f, 0.f, 0.f, 0.f};
  #pragma unroll
  for (int k = 0; k < 4; k++){
    int s = tokslot[t * 4 + k];
    float w = topk_w[t * 4 + k];
    float4 v = reinterpret_cast<const float4*>(outs + (size_t)s * DM)[j];
    o.x += w * v.x; o.y += w * v.y; o.z += w * v.z; o.w += w * v.w;
  }
  reinterpret_cast<float4*>(out + (size_t)t * DM)[j] = o;
}

// ---------------- workspace layout (bytes) ----------------
#define WS_OFFS    64
#define WS_CURSOR  192
#define WS_TOPKE   256
#define WS_TOPKW   (WS_TOPKE + NSLOT * 4)
#define WS_TOKSLOT (WS_TOPKW + NSLOT * 4)
#define WS_XG      131072
#define WS_ACT     (WS_XG + (size_t)SLOTPAD * DM * 2)      // 6,447,104
#define WS_OUTS    (WS_ACT + (size_t)SLOTPAD * FFN * 2)    // 31,711,232
// total: WS_OUTS + 4096*768*4 = 44,294,144 bytes

extern "C" void kernel_launch(void* const* d_in, const int* in_sizes, int n_in,
                              void* d_out, int out_size, void* d_ws, size_t ws_size,
                              hipStream_t stream){
  const float* x  = (const float*)d_in[0];   // [1024, 768]
  const float* rw = (const float*)d_in[1];   // [16, 768]
  const float* w1 = (const float*)d_in[2];   // [16, 3072, 768]
  const float* v1 = (const float*)d_in[3];   // [16, 3072, 768]
  const float* w2 = (const float*)d_in[4];   // [16, 768, 3072]
  float* out = (float*)d_out;
  char* ws = (char*)d_ws;

  int*   offs    = (int*)(ws + WS_OFFS);
  int*   cursor  = (int*)(ws + WS_CURSOR);
  int*   topk_e  = (int*)(ws + WS_TOPKE);
  float* topk_w  = (float*)(ws + WS_TOPKW);
  int*   tokslot = (int*)(ws + WS_TOKSLOT);
  unsigned short* xg  = (unsigned short*)(ws + WS_XG);
  unsigned short* act = (unsigned short*)(ws + WS_ACT);
  float* outs = (float*)(ws + WS_OUTS);

  k_router<<<dim3(NTOK), dim3(64), 0, stream>>>(x, rw, topk_e, topk_w);
  k_prep<<<dim3(1), dim3(256), 0, stream>>>(topk_e, offs, cursor);
  k_assign_gather<<<dim3(NTOK), dim3(192), 0, stream>>>(x, topk_e, cursor, tokslot, xg);
  k_ffn1<<<dim3(FFN / 32, NEXP), dim3(256), 0, stream>>>(w1, v1, xg, act, offs);
  k_ffn2<<<dim3(DM / 32, NEXP), dim3(256), 0, stream>>>(w2, act, outs, offs);
  k_combine<<<dim3(NTOK), dim3(192), 0, stream>>>(outs, tokslot, topk_w, out);
}